// Round 11
// baseline (224.091 us; speedup 1.0000x reference)
//
#include <hip/hip_runtime.h>
#include <hip/hip_bf16.h>

#define NEG_SLOP 0.2f
typedef unsigned long long ull;
typedef __attribute__((ext_vector_type(8))) short bf16x8;
typedef __attribute__((ext_vector_type(4))) float f32x4;

__device__ __forceinline__ float lrelu(float v) { return v > 0.0f ? v : NEG_SLOP * v; }

__device__ __forceinline__ float bf2f(unsigned short u) {
    union { unsigned int i; float f; } c; c.i = ((unsigned int)u) << 16; return c.f;
}
__device__ __forceinline__ unsigned short f2bf(float f) {
    union { float f; unsigned int i; } c; c.f = f;
    unsigned int r = c.i + 0x7FFF + ((c.i >> 16) & 1);  // round-nearest-even
    return (unsigned short)(r >> 16);
}

struct us8 { ushort4 a, b; };

// non-temporal 8B load of an edge record (stream data: don't pollute L2, keep it for hb)
__device__ __forceinline__ int2 ld_nt_i2(const int2* p) {
    long long v = __builtin_nontemporal_load((const long long*)p);
    int2 r; r.x = (int)(v & 0xffffffffLL); r.y = (int)(v >> 32); return r;
}

// ---------------- prep: zero packed4 + all weight converts/transposes to bf16 ----------------
__global__ void prep_kernel(const float* __restrict__ Wh, unsigned short* __restrict__ wht,
                            const float* __restrict__ W1, unsigned short* __restrict__ w1t,
                            const float* __restrict__ W2, unsigned short* __restrict__ w2t,
                            const float* __restrict__ W3, unsigned short* __restrict__ w3t,
                            const float* __restrict__ W4, unsigned short* __restrict__ w4t,
                            float4* __restrict__ pz, int nz) {
    int idx = blockIdx.x * 256 + threadIdx.x;
    if (idx < nz) pz[idx] = make_float4(0.f, 0.f, 0.f, 0.f);
    if (idx < 256 * 128) {             // WhT[c][k] = Wh[k][c]
        int k = idx >> 7, c = idx & 127;
        wht[(size_t)c * 256 + k] = f2bf(Wh[idx]);
    }
    if (idx < 64 * 128) {              // W1T[c][k] = W1[k][c]
        int c = idx >> 7, k = idx & 127;
        w1t[idx] = f2bf(W1[k * 64 + c]);
    }
    if (idx < 64 * 64) {               // W{2,3,4}T[c][k]
        int c = idx >> 6, k = idx & 63;
        w2t[idx] = f2bf(W2[k * 64 + c]);
        w3t[idx] = f2bf(W3[k * 64 + c]);
        w4t[idx] = f2bf(W4[k * 64 + c]);
    }
}

// ---------------- histogram: 4 shadow copies, packed (cnt<<40 | fp32.32 wsum), emits rank ----------------
__global__ void histo_kernel(const int* __restrict__ dst, const float* __restrict__ ew,
                             ull* __restrict__ packed4, int* __restrict__ rank,
                             int n_edges, int n) {
    int e = blockIdx.x * 256 + threadIdx.x;
    if (e >= n_edges) return;
    int d = dst[e];
    int c = e & 3;
    ull delta = (1ULL << 40) | (ull)(ew[e] * 4294967296.0f);
    ull old = atomicAdd(&packed4[(size_t)c * n + d], delta);
    rank[e] = (int)(old >> 40);
}

// ---- scan1: per-1024-node block scan of total counts; emits relative per-copy bases + dinv ----
__global__ void scan1_kernel(const ull* __restrict__ packed4, int* __restrict__ pre,
                             int4* __restrict__ bases, int* __restrict__ bsum,
                             float* __restrict__ dinv, int n) {
    __shared__ int s[256];
    int t = threadIdx.x;
    int base = blockIdx.x * 1024 + t * 4;
    const ull m = (1ULL << 40) - 1;
    int tot[4];
#pragma unroll
    for (int j = 0; j < 4; ++j) {
        int node = base + j;
        if (node < n) {
            ull p0 = packed4[node];
            ull p1 = packed4[(size_t)n + node];
            ull p2 = packed4[2 * (size_t)n + node];
            ull p3 = packed4[3 * (size_t)n + node];
            int c0 = (int)(p0 >> 40), c1 = (int)(p1 >> 40);
            int c2 = (int)(p2 >> 40), c3 = (int)(p3 >> 40);
            bases[node] = make_int4(0, c0, c0 + c1, c0 + c1 + c2);
            tot[j] = c0 + c1 + c2 + c3;
            float deg = (float)((p0 & m) + (p1 & m) + (p2 & m) + (p3 & m)) *
                        (1.0f / 4294967296.0f);
            dinv[node] = rsqrtf(deg + 1.0f);
        } else tot[j] = 0;
    }
    int tsum = tot[0] + tot[1] + tot[2] + tot[3];
    s[t] = tsum;
    __syncthreads();
    for (int off = 1; off < 256; off <<= 1) {
        int v = (t >= off) ? s[t - off] : 0;
        __syncthreads();
        s[t] += v;
        __syncthreads();
    }
    int ex = s[t] - tsum;
    if (t == 255) bsum[blockIdx.x] = s[255];
    int o[4];
    o[0] = ex; o[1] = ex + tot[0]; o[2] = o[1] + tot[1]; o[3] = o[2] + tot[2];
    if (base + 3 < n) *(int4*)&pre[base] = make_int4(o[0], o[1], o[2], o[3]);
    else {
        for (int j = 0; j < 4; ++j) if (base + j < n) pre[base + j] = o[j];
    }
}

// ---- scan3: redundant per-block scan of bsum (replaces scan2), absolute rp + absolute bases ----
__global__ void scan3_kernel(int* __restrict__ rp, int4* __restrict__ bases,
                             const int* __restrict__ bsum, int nbsum,
                             int n, int n_edges) {
    __shared__ int sb[64];
    __shared__ int boffs[64];
    int t = threadIdx.x;
    int myv = 0;
    if (t < 64) { myv = (t < nbsum) ? bsum[t] : 0; sb[t] = myv; }
    __syncthreads();
    for (int off = 1; off < 64; off <<= 1) {
        int u = (t >= off && t < 64) ? sb[t - off] : 0;
        __syncthreads();
        if (t < 64) sb[t] += u;
        __syncthreads();
    }
    if (t < 64) boffs[t] = sb[t] - myv;   // exclusive prefix of block sums
    __syncthreads();
    int idx = blockIdx.x * 256 + t;
    int base = idx * 4;
    if (base >= n) {
        if (base == ((n + 3) & ~3)) rp[n] = n_edges;
        return;
    }
    int boff = boffs[(base >> 10) & 63];
    if (base + 3 < n) {
        int4 v = *(int4*)&rp[base];
        v.x += boff; v.y += boff; v.z += boff; v.w += boff;
        *(int4*)&rp[base] = v;
        int va[4] = {v.x, v.y, v.z, v.w};
#pragma unroll
        for (int j = 0; j < 4; ++j) {
            int4 bs = bases[base + j];
            bs.x += va[j]; bs.y += va[j]; bs.z += va[j]; bs.w += va[j];
            bases[base + j] = bs;
        }
    } else {
        for (int j = 0; j < 4 && base + j < n; ++j) {
            int v = rp[base + j] + boff;
            rp[base + j] = v;
            int4 bs = bases[base + j];
            bs.x += v; bs.y += v; bs.z += v; bs.w += v;
            bases[base + j] = bs;
        }
        rp[n] = n_edges;
    }
}

// ---------------- CSR fill: atomic-free; bases are absolute slot starts per copy ----------------
__global__ void fill_kernel(const int* __restrict__ src, const int* __restrict__ dst,
                            const float* __restrict__ ew, const int* __restrict__ rank,
                            const int4* __restrict__ bases,
                            int2* __restrict__ e_sw, int n_edges) {
    int e = blockIdx.x * 256 + threadIdx.x;
    if (e >= n_edges) return;
    int d = dst[e];
    int c = e & 3;
    int4 bs = bases[d];
    int b = (c == 0) ? bs.x : (c == 1) ? bs.y : (c == 2) ? bs.z : bs.w;
    e_sw[b + rank[e]] = make_int2(src[e], __float_as_int(ew[e]));
}

// ---------------- gathers: wave/node, 8 edge-groups x 8 feature-lanes, NT edge loads ----------------
__global__ void gather_plain(const int* __restrict__ rp, const int2* __restrict__ e_sw,
                             const unsigned short* __restrict__ hb,
                             const float* __restrict__ b, unsigned short* __restrict__ cat, int n) {
    int node = (blockIdx.x * 256 + threadIdx.x) >> 6;
    if (node >= n) return;
    int lane = threadIdx.x & 63;
    int eg = lane >> 3;
    int f0 = (lane & 7) * 8;
    int lo = rp[node], hi = rp[node + 1];
    float a[8] = {};
    for (int k = lo + eg; k < hi; k += 16) {
        int k1 = k + 8;
        int2 p0 = ld_nt_i2(&e_sw[k]);
        int2 p1 = ld_nt_i2(&e_sw[k1 < hi ? k1 : k]);
        float w0 = __int_as_float(p0.y);
        float w1 = k1 < hi ? __int_as_float(p1.y) : 0.f;
        us8 u0 = *(const us8*)&hb[(size_t)p0.x * 64 + f0];
        us8 u1 = *(const us8*)&hb[(size_t)p1.x * 64 + f0];
        a[0] += w0 * bf2f(u0.a.x) + w1 * bf2f(u1.a.x);
        a[1] += w0 * bf2f(u0.a.y) + w1 * bf2f(u1.a.y);
        a[2] += w0 * bf2f(u0.a.z) + w1 * bf2f(u1.a.z);
        a[3] += w0 * bf2f(u0.a.w) + w1 * bf2f(u1.a.w);
        a[4] += w0 * bf2f(u0.b.x) + w1 * bf2f(u1.b.x);
        a[5] += w0 * bf2f(u0.b.y) + w1 * bf2f(u1.b.y);
        a[6] += w0 * bf2f(u0.b.z) + w1 * bf2f(u1.b.z);
        a[7] += w0 * bf2f(u0.b.w) + w1 * bf2f(u1.b.w);
    }
#pragma unroll
    for (int j = 0; j < 8; ++j) {
        a[j] += __shfl_xor(a[j], 8, 64);
        a[j] += __shfl_xor(a[j], 16, 64);
        a[j] += __shfl_xor(a[j], 32, 64);
    }
    if (eg == 0) {
        unsigned short o[8];
#pragma unroll
        for (int j = 0; j < 8; ++j) o[j] = f2bf(lrelu(a[j] + b[f0 + j]));
        *(int4*)&cat[(size_t)node * 256 + f0] = *(int4*)o;
    }
}

// hb holds hb2 = dinv[row]*(h@W); result = lrelu(dinv[d]*(sum + hb2[d]) + b)
__global__ void gather_norm(const int* __restrict__ rp, const int2* __restrict__ e_sw,
                            const unsigned short* __restrict__ hb,
                            const float* __restrict__ dinv, const float* __restrict__ b,
                            unsigned short* __restrict__ cat, int col_off, int n) {
    int node = (blockIdx.x * 256 + threadIdx.x) >> 6;
    if (node >= n) return;
    int lane = threadIdx.x & 63;
    int eg = lane >> 3;
    int f0 = (lane & 7) * 8;
    // hoisted: independent of the rp -> edge -> hb chain, overlap their latency
    float di = dinv[node];
    us8 h = *(const us8*)&hb[(size_t)node * 64 + f0];
    int lo = rp[node], hi = rp[node + 1];
    float a[8] = {};
    for (int k = lo + eg; k < hi; k += 16) {
        int k1 = k + 8;
        int2 p0 = ld_nt_i2(&e_sw[k]);
        int2 p1 = ld_nt_i2(&e_sw[k1 < hi ? k1 : k]);
        float w0 = __int_as_float(p0.y);
        float w1 = k1 < hi ? __int_as_float(p1.y) : 0.f;
        us8 u0 = *(const us8*)&hb[(size_t)p0.x * 64 + f0];
        us8 u1 = *(const us8*)&hb[(size_t)p1.x * 64 + f0];
        a[0] += w0 * bf2f(u0.a.x) + w1 * bf2f(u1.a.x);
        a[1] += w0 * bf2f(u0.a.y) + w1 * bf2f(u1.a.y);
        a[2] += w0 * bf2f(u0.a.z) + w1 * bf2f(u1.a.z);
        a[3] += w0 * bf2f(u0.a.w) + w1 * bf2f(u1.a.w);
        a[4] += w0 * bf2f(u0.b.x) + w1 * bf2f(u1.b.x);
        a[5] += w0 * bf2f(u0.b.y) + w1 * bf2f(u1.b.y);
        a[6] += w0 * bf2f(u0.b.z) + w1 * bf2f(u1.b.z);
        a[7] += w0 * bf2f(u0.b.w) + w1 * bf2f(u1.b.w);
    }
#pragma unroll
    for (int j = 0; j < 8; ++j) {
        a[j] += __shfl_xor(a[j], 8, 64);
        a[j] += __shfl_xor(a[j], 16, 64);
        a[j] += __shfl_xor(a[j], 32, 64);
    }
    if (eg == 0) {
        float hs[8] = {bf2f(h.a.x), bf2f(h.a.y), bf2f(h.a.z), bf2f(h.a.w),
                       bf2f(h.b.x), bf2f(h.b.y), bf2f(h.b.z), bf2f(h.b.w)};
        unsigned short o[8];
#pragma unroll
        for (int j = 0; j < 8; ++j) o[j] = f2bf(lrelu(di * (a[j] + hs[j]) + b[f0 + j]));
        *(int4*)&cat[(size_t)node * 256 + col_off + f0] = *(int4*)o;
    }
}

// ---------------- MFMA hid GEMM (layers 2-4): cat-col[N x 64](bf16) @ W[64 x 64] -> dinv*out bf16 ----------------
__global__ __launch_bounds__(256) void gemm_hid_mfma(
    const unsigned short* __restrict__ in, int in_stride,
    const unsigned short* __restrict__ wT, const float* __restrict__ dinv,
    unsigned short* __restrict__ outb, int n_rows) {
    __shared__ __align__(16) char As[64 * 128];
    __shared__ __align__(16) char Bs[64 * 128];
    const int tid = threadIdx.x;
    const int wid = tid >> 6, lane = tid & 63;
    const int row0 = blockIdx.x * 64;
    const int lrow = lane & 15, kg = lane >> 4;
    {
        int row = tid >> 2, seg = tid & 3;
        int rr = row0 + row; if (rr >= n_rows) rr = n_rows - 1;
        const int4* g = (const int4*)&in[(size_t)rr * in_stride + seg * 16];
        int4 u0 = g[0], u1 = g[1];
        const int4* gb = (const int4*)&wT[(size_t)row * 64 + seg * 16];
        int4 v0 = gb[0], v1 = gb[1];
        int sw = (row & 7) << 4;
        int base = row * 128 + seg * 32;
        *(int4*)(As + (base ^ sw)) = u0;
        *(int4*)(As + ((base + 16) ^ sw)) = u1;
        *(int4*)(Bs + (base ^ sw)) = v0;
        *(int4*)(Bs + ((base + 16) ^ sw)) = v1;
    }
    __syncthreads();
    int arow = wid * 16 + lrow;
    int asw = (arow & 7) << 4;
    f32x4 acc[4] = {};
#pragma unroll
    for (int ks = 0; ks < 2; ++ks) {
        bf16x8 af = *(bf16x8*)(As + ((arow * 128 + ks * 64 + kg * 16) ^ asw));
#pragma unroll
        for (int cf = 0; cf < 4; ++cf) {
            int c = cf * 16 + lrow;
            bf16x8 bf = *(bf16x8*)(Bs + ((c * 128 + ks * 64 + kg * 16) ^ ((c & 7) << 4)));
            acc[cf] = __builtin_amdgcn_mfma_f32_16x16x32_bf16(af, bf, acc[cf], 0, 0, 0);
        }
    }
    int r4 = (lane >> 4) * 4;
#pragma unroll
    for (int reg = 0; reg < 4; ++reg) {
        int r = row0 + wid * 16 + r4 + reg;
        if (r >= n_rows) continue;
        float di = dinv[r];
#pragma unroll
        for (int cf = 0; cf < 4; ++cf)
            outb[(size_t)r * 64 + cf * 16 + lrow] = f2bf(acc[cf][reg] * di);
    }
}

// ---------------- MFMA layer-1 GEMM: x[N x 128](fp32) @ W1[128 x 64] -> bf16 hb ----------------
__global__ __launch_bounds__(256) void gemm_hid_mfma_x(
    const float* __restrict__ x, const unsigned short* __restrict__ w1T,
    unsigned short* __restrict__ outb, int n_rows) {
    __shared__ __align__(16) char As[64 * 256];
    __shared__ __align__(16) char Bs[64 * 256];
    const int tid = threadIdx.x;
    const int wid = tid >> 6, lane = tid & 63;
    const int row0 = blockIdx.x * 64;
    const int lrow = lane & 15, kg = lane >> 4;
    {
        int row = tid >> 2, seg = tid & 3;
        int rr = row0 + row; if (rr >= n_rows) rr = n_rows - 1;
        const float4* g = (const float4*)&x[(size_t)rr * 128 + seg * 32];
        const int4* gb = (const int4*)&w1T[(size_t)row * 128 + seg * 32];
        int sw = (row & 7) << 4;
        int base = row * 256 + seg * 64;
#pragma unroll
        for (int i = 0; i < 4; ++i) {
            float4 f0 = g[2 * i], f1 = g[2 * i + 1];
            unsigned short u[8] = {f2bf(f0.x), f2bf(f0.y), f2bf(f0.z), f2bf(f0.w),
                                   f2bf(f1.x), f2bf(f1.y), f2bf(f1.z), f2bf(f1.w)};
            *(int4*)(As + ((base + i * 16) ^ sw)) = *(int4*)u;
            *(int4*)(Bs + ((base + i * 16) ^ sw)) = gb[i];
        }
    }
    __syncthreads();
    int arow = wid * 16 + lrow;
    int asw = (arow & 7) << 4;
    f32x4 acc[4] = {};
#pragma unroll
    for (int ks = 0; ks < 4; ++ks) {
        bf16x8 af = *(bf16x8*)(As + ((arow * 256 + ks * 64 + kg * 16) ^ asw));
#pragma unroll
        for (int cf = 0; cf < 4; ++cf) {
            int c = cf * 16 + lrow;
            bf16x8 bf = *(bf16x8*)(Bs + ((c * 256 + ks * 64 + kg * 16) ^ ((c & 7) << 4)));
            acc[cf] = __builtin_amdgcn_mfma_f32_16x16x32_bf16(af, bf, acc[cf], 0, 0, 0);
        }
    }
    int r4 = (lane >> 4) * 4;
#pragma unroll
    for (int reg = 0; reg < 4; ++reg) {
        int r = row0 + wid * 16 + r4 + reg;
        if (r >= n_rows) continue;
#pragma unroll
        for (int cf = 0; cf < 4; ++cf)
            outb[(size_t)r * 64 + cf * 16 + lrow] = f2bf(acc[cf][reg]);
    }
}

// ---------------- final GEMM via MFMA: cat(bf16)[N x 256] @ Wh[256 x 128] + bh ----------------
__global__ __launch_bounds__(256) void gemm_out_mfma(
    const unsigned short* __restrict__ cat, const unsigned short* __restrict__ whT,
    const float* __restrict__ bh, float* __restrict__ out, int n_rows) {
    __shared__ __align__(16) char As[64 * 128];
    __shared__ __align__(16) char Bs[128 * 128];
    const int tid = threadIdx.x;
    const int wid = tid >> 6, lane = tid & 63;
    const int row0 = blockIdx.x * 64;
    const int lrow = lane & 15, kg = lane >> 4;
    f32x4 acc[8] = {};
    for (int kc = 0; kc < 4; ++kc) {
        __syncthreads();
        {
            int row = tid >> 2, seg = tid & 3;
            int rr = row0 + row; if (rr >= n_rows) rr = n_rows - 1;
            const int4* g = (const int4*)&cat[(size_t)rr * 256 + kc * 64 + seg * 16];
            int4 u0 = g[0], u1 = g[1];
            int sw = (row & 7) << 4;
            int base = row * 128 + seg * 32;
            *(int4*)(As + (base ^ sw)) = u0;
            *(int4*)(As + ((base + 16) ^ sw)) = u1;
        }
        {
            int c = tid >> 1, seg = tid & 1;
            const int4* g = (const int4*)&whT[(size_t)c * 256 + kc * 64 + seg * 32];
            int sw = (c & 7) << 4;
            int base = c * 128 + seg * 64;
#pragma unroll
            for (int i = 0; i < 4; ++i)
                *(int4*)(Bs + ((base + i * 16) ^ sw)) = g[i];
        }
        __syncthreads();
        int arow = wid * 16 + lrow;
        int asw = (arow & 7) << 4;
#pragma unroll
        for (int ks = 0; ks < 2; ++ks) {
            bf16x8 af = *(bf16x8*)(As + ((arow * 128 + ks * 64 + kg * 16) ^ asw));
#pragma unroll
            for (int cf = 0; cf < 8; ++cf) {
                int c = cf * 16 + lrow;
                bf16x8 bf = *(bf16x8*)(Bs + ((c * 128 + ks * 64 + kg * 16) ^ ((c & 7) << 4)));
                acc[cf] = __builtin_amdgcn_mfma_f32_16x16x32_bf16(af, bf, acc[cf], 0, 0, 0);
            }
        }
    }
    int lrow4 = (lane >> 4) * 4;
#pragma unroll
    for (int cf = 0; cf < 8; ++cf) {
        int col = cf * 16 + lrow;
        float bias = bh[col];
#pragma unroll
        for (int reg = 0; reg < 4; ++reg) {
            int r = row0 + wid * 16 + lrow4 + reg;
            if (r < n_rows) out[(size_t)r * 128 + col] = acc[cf][reg] + bias;
        }
    }
}

extern "C" void kernel_launch(void* const* d_in, const int* in_sizes, int n_in,
                              void* d_out, int out_size, void* d_ws, size_t ws_size,
                              hipStream_t stream) {
    const float* x  = (const float*)d_in[0];
    const int*   ei = (const int*)d_in[1];
    const float* ew = (const float*)d_in[2];
    const float* W1 = (const float*)d_in[3];
    const float* b1 = (const float*)d_in[4];
    const float* W2 = (const float*)d_in[5];
    const float* b2 = (const float*)d_in[6];
    const float* W3 = (const float*)d_in[7];
    const float* b3 = (const float*)d_in[8];
    const float* W4 = (const float*)d_in[9];
    const float* b4 = (const float*)d_in[10];
    const float* Wh = (const float*)d_in[11];
    const float* bh = (const float*)d_in[12];

    const int E = in_sizes[2];          // 800000
    const int N = in_sizes[0] / 128;    // 50000
    const int* src = ei;
    const int* dst = ei + E;

    char* p = (char*)d_ws;
    unsigned short* cat     = (unsigned short*)p; p += (size_t)N * 256 * 2;
    unsigned short* hb      = (unsigned short*)p; p += (size_t)N * 64 * 2;
    unsigned short* wht     = (unsigned short*)p; p += (size_t)128 * 256 * 2;
    unsigned short* w1t     = (unsigned short*)p; p += (size_t)64 * 128 * 2;
    unsigned short* w2t     = (unsigned short*)p; p += (size_t)64 * 64 * 2;
    unsigned short* w3t     = (unsigned short*)p; p += (size_t)64 * 64 * 2;
    unsigned short* w4t     = (unsigned short*)p; p += (size_t)64 * 64 * 2;
    ull*            packed4 = (ull*)p;            p += (size_t)N * 4 * 8;
    float*          dinv    = (float*)p;          p += (size_t)N * 4;
    int*            row_ptr = (int*)p;            p += (size_t)(N + 4) * 4;
    int*            bsum    = (int*)p;            p += (size_t)64 * 4;
    int4*           bases   = (int4*)p;           p += (size_t)N * 16;
    int*            rank    = (int*)p;            p += (size_t)E * 4;
    int2*           e_sw    = (int2*)p;           p += (size_t)E * 8;
    float* out = (float*)d_out;

    int eb   = (E + 255) / 256;
    int nb64 = (N * 64 + 255) / 256;
    int gb64 = (N + 63) / 64;
    int sb   = (N + 1023) / 1024;       // <= 64
    int s3b  = ((N + 3) / 4 + 256) / 256;
    int nz   = N * 2;
    int pb   = (nz > 256 * 128 ? nz : 256 * 128) / 256 + 1;

    // ---- prep + CSR build (scan2 folded into scan3) ----
    prep_kernel<<<pb, 256, 0, stream>>>(Wh, wht, W1, w1t, W2, w2t, W3, w3t, W4, w4t,
                                        (float4*)packed4, nz);
    histo_kernel<<<eb, 256, 0, stream>>>(dst, ew, packed4, rank, E, N);
    scan1_kernel<<<sb, 256, 0, stream>>>(packed4, row_ptr, bases, bsum, dinv, N);
    scan3_kernel<<<s3b, 256, 0, stream>>>(row_ptr, bases, bsum, sb, N, E);
    fill_kernel<<<eb, 256, 0, stream>>>(src, dst, ew, rank, bases, e_sw, E);

    // ---- layer 1 (no norm) ----
    gemm_hid_mfma_x<<<gb64, 256, 0, stream>>>(x, w1t, hb, N);
    gather_plain<<<nb64, 256, 0, stream>>>(row_ptr, e_sw, hb, b1, cat, N);

    // ---- layers 2-4 (normalized; hb holds dinv-scaled hidden) ----
    const unsigned short* Wt[3] = {w2t, w3t, w4t};
    const float* bl[3] = {b2, b3, b4};
    for (int l = 1; l < 4; ++l) {
        gemm_hid_mfma<<<gb64, 256, 0, stream>>>(cat + (size_t)(l - 1) * 64, 256,
                                                Wt[l - 1], dinv, hb, N);
        gather_norm<<<nb64, 256, 0, stream>>>(row_ptr, e_sw, hb, dinv,
                                              bl[l - 1], cat, l * 64, N);
    }

    // ---- final projection (MFMA) ----
    gemm_out_mfma<<<gb64, 256, 0, stream>>>(cat, wht, bh, out, N);
}

// Round 12
// 210.326 us; speedup vs baseline: 1.0654x; 1.0654x over previous
//
#include <hip/hip_runtime.h>
#include <hip/hip_bf16.h>

#define NEG_SLOP 0.2f
typedef unsigned long long ull;
typedef __attribute__((ext_vector_type(8))) short bf16x8;
typedef __attribute__((ext_vector_type(4))) float f32x4;

__device__ __forceinline__ float lrelu(float v) { return v > 0.0f ? v : NEG_SLOP * v; }

__device__ __forceinline__ float bf2f(unsigned short u) {
    union { unsigned int i; float f; } c; c.i = ((unsigned int)u) << 16; return c.f;
}
__device__ __forceinline__ unsigned short f2bf(float f) {
    union { float f; unsigned int i; } c; c.f = f;
    unsigned int r = c.i + 0x7FFF + ((c.i >> 16) & 1);  // round-nearest-even
    return (unsigned short)(r >> 16);
}

struct us8 { ushort4 a, b; };

// ---------------- prep: zero packed4 + all weight converts/transposes to bf16 ----------------
__global__ void prep_kernel(const float* __restrict__ Wh, unsigned short* __restrict__ wht,
                            const float* __restrict__ W1, unsigned short* __restrict__ w1t,
                            const float* __restrict__ W2, unsigned short* __restrict__ w2t,
                            const float* __restrict__ W3, unsigned short* __restrict__ w3t,
                            const float* __restrict__ W4, unsigned short* __restrict__ w4t,
                            float4* __restrict__ pz, int nz) {
    int idx = blockIdx.x * 256 + threadIdx.x;
    if (idx < nz) pz[idx] = make_float4(0.f, 0.f, 0.f, 0.f);
    if (idx < 256 * 128) {             // WhT[c][k] = Wh[k][c]
        int k = idx >> 7, c = idx & 127;
        wht[(size_t)c * 256 + k] = f2bf(Wh[idx]);
    }
    if (idx < 64 * 128) {              // W1T[c][k] = W1[k][c]
        int c = idx >> 7, k = idx & 127;
        w1t[idx] = f2bf(W1[k * 64 + c]);
    }
    if (idx < 64 * 64) {               // W{2,3,4}T[c][k]
        int c = idx >> 6, k = idx & 63;
        w2t[idx] = f2bf(W2[k * 64 + c]);
        w3t[idx] = f2bf(W3[k * 64 + c]);
        w4t[idx] = f2bf(W4[k * 64 + c]);
    }
}

// ---------------- histogram: 4 shadow copies, packed (cnt<<40 | fp32.32 wsum), emits rank ----------------
__global__ void histo_kernel(const int* __restrict__ dst, const float* __restrict__ ew,
                             ull* __restrict__ packed4, int* __restrict__ rank,
                             int n_edges, int n) {
    int e = blockIdx.x * 256 + threadIdx.x;
    if (e >= n_edges) return;
    int d = dst[e];
    int c = e & 3;
    ull delta = (1ULL << 40) | (ull)(ew[e] * 4294967296.0f);
    ull old = atomicAdd(&packed4[(size_t)c * n + d], delta);
    rank[e] = (int)(old >> 40);
}

// ---- scan1: per-1024-node block scan of total counts; emits relative per-copy bases + dinv ----
__global__ void scan1_kernel(const ull* __restrict__ packed4, int* __restrict__ pre,
                             int4* __restrict__ bases, int* __restrict__ bsum,
                             float* __restrict__ dinv, int n) {
    __shared__ int s[256];
    int t = threadIdx.x;
    int base = blockIdx.x * 1024 + t * 4;
    const ull m = (1ULL << 40) - 1;
    int tot[4];
#pragma unroll
    for (int j = 0; j < 4; ++j) {
        int node = base + j;
        if (node < n) {
            ull p0 = packed4[node];
            ull p1 = packed4[(size_t)n + node];
            ull p2 = packed4[2 * (size_t)n + node];
            ull p3 = packed4[3 * (size_t)n + node];
            int c0 = (int)(p0 >> 40), c1 = (int)(p1 >> 40);
            int c2 = (int)(p2 >> 40), c3 = (int)(p3 >> 40);
            bases[node] = make_int4(0, c0, c0 + c1, c0 + c1 + c2);
            tot[j] = c0 + c1 + c2 + c3;
            float deg = (float)((p0 & m) + (p1 & m) + (p2 & m) + (p3 & m)) *
                        (1.0f / 4294967296.0f);
            dinv[node] = rsqrtf(deg + 1.0f);
        } else tot[j] = 0;
    }
    int tsum = tot[0] + tot[1] + tot[2] + tot[3];
    s[t] = tsum;
    __syncthreads();
    for (int off = 1; off < 256; off <<= 1) {
        int v = (t >= off) ? s[t - off] : 0;
        __syncthreads();
        s[t] += v;
        __syncthreads();
    }
    int ex = s[t] - tsum;
    if (t == 255) bsum[blockIdx.x] = s[255];
    int o[4];
    o[0] = ex; o[1] = ex + tot[0]; o[2] = o[1] + tot[1]; o[3] = o[2] + tot[2];
    if (base + 3 < n) *(int4*)&pre[base] = make_int4(o[0], o[1], o[2], o[3]);
    else {
        for (int j = 0; j < 4; ++j) if (base + j < n) pre[base + j] = o[j];
    }
}

// ---- scan3: redundant per-block scan of bsum (replaces scan2), absolute rp + absolute bases ----
__global__ void scan3_kernel(int* __restrict__ rp, int4* __restrict__ bases,
                             const int* __restrict__ bsum, int nbsum,
                             int n, int n_edges) {
    __shared__ int sb[64];
    __shared__ int boffs[64];
    int t = threadIdx.x;
    int myv = 0;
    if (t < 64) { myv = (t < nbsum) ? bsum[t] : 0; sb[t] = myv; }
    __syncthreads();
    for (int off = 1; off < 64; off <<= 1) {
        int u = (t >= off && t < 64) ? sb[t - off] : 0;
        __syncthreads();
        if (t < 64) sb[t] += u;
        __syncthreads();
    }
    if (t < 64) boffs[t] = sb[t] - myv;   // exclusive prefix of block sums
    __syncthreads();
    int idx = blockIdx.x * 256 + t;
    int base = idx * 4;
    if (base >= n) {
        if (base == ((n + 3) & ~3)) rp[n] = n_edges;
        return;
    }
    int boff = boffs[(base >> 10) & 63];
    if (base + 3 < n) {
        int4 v = *(int4*)&rp[base];
        v.x += boff; v.y += boff; v.z += boff; v.w += boff;
        *(int4*)&rp[base] = v;
        int va[4] = {v.x, v.y, v.z, v.w};
#pragma unroll
        for (int j = 0; j < 4; ++j) {
            int4 bs = bases[base + j];
            bs.x += va[j]; bs.y += va[j]; bs.z += va[j]; bs.w += va[j];
            bases[base + j] = bs;
        }
    } else {
        for (int j = 0; j < 4 && base + j < n; ++j) {
            int v = rp[base + j] + boff;
            rp[base + j] = v;
            int4 bs = bases[base + j];
            bs.x += v; bs.y += v; bs.z += v; bs.w += v;
            bases[base + j] = bs;
        }
        rp[n] = n_edges;
    }
}

// ---------------- CSR fill: atomic-free; bases are absolute slot starts per copy ----------------
__global__ void fill_kernel(const int* __restrict__ src, const int* __restrict__ dst,
                            const float* __restrict__ ew, const int* __restrict__ rank,
                            const int4* __restrict__ bases,
                            int2* __restrict__ e_sw, int n_edges) {
    int e = blockIdx.x * 256 + threadIdx.x;
    if (e >= n_edges) return;
    int d = dst[e];
    int c = e & 3;
    int4 bs = bases[d];
    int b = (c == 0) ? bs.x : (c == 1) ? bs.y : (c == 2) ? bs.z : bs.w;
    e_sw[b + rank[e]] = make_int2(src[e], __float_as_int(ew[e]));
}

// ---------------- gathers: wave/node, 8 edge-groups x 8 feature-lanes (16B/lane) ----------------
__global__ void gather_plain(const int* __restrict__ rp, const int2* __restrict__ e_sw,
                             const unsigned short* __restrict__ hb,
                             const float* __restrict__ b, unsigned short* __restrict__ cat, int n) {
    int node = (blockIdx.x * 256 + threadIdx.x) >> 6;
    if (node >= n) return;
    int lane = threadIdx.x & 63;
    int eg = lane >> 3;
    int f0 = (lane & 7) * 8;
    int lo = rp[node], hi = rp[node + 1];
    float a[8] = {};
    for (int k = lo + eg; k < hi; k += 16) {
        int k1 = k + 8;
        int2 p0 = e_sw[k];
        int2 p1 = e_sw[k1 < hi ? k1 : k];
        float w0 = __int_as_float(p0.y);
        float w1 = k1 < hi ? __int_as_float(p1.y) : 0.f;
        us8 u0 = *(const us8*)&hb[(size_t)p0.x * 64 + f0];
        us8 u1 = *(const us8*)&hb[(size_t)p1.x * 64 + f0];
        a[0] += w0 * bf2f(u0.a.x) + w1 * bf2f(u1.a.x);
        a[1] += w0 * bf2f(u0.a.y) + w1 * bf2f(u1.a.y);
        a[2] += w0 * bf2f(u0.a.z) + w1 * bf2f(u1.a.z);
        a[3] += w0 * bf2f(u0.a.w) + w1 * bf2f(u1.a.w);
        a[4] += w0 * bf2f(u0.b.x) + w1 * bf2f(u1.b.x);
        a[5] += w0 * bf2f(u0.b.y) + w1 * bf2f(u1.b.y);
        a[6] += w0 * bf2f(u0.b.z) + w1 * bf2f(u1.b.z);
        a[7] += w0 * bf2f(u0.b.w) + w1 * bf2f(u1.b.w);
    }
#pragma unroll
    for (int j = 0; j < 8; ++j) {
        a[j] += __shfl_xor(a[j], 8, 64);
        a[j] += __shfl_xor(a[j], 16, 64);
        a[j] += __shfl_xor(a[j], 32, 64);
    }
    if (eg == 0) {
        unsigned short o[8];
#pragma unroll
        for (int j = 0; j < 8; ++j) o[j] = f2bf(lrelu(a[j] + b[f0 + j]));
        *(int4*)&cat[(size_t)node * 256 + f0] = *(int4*)o;
    }
}

// hb holds hb2 = dinv[row]*(h@W); result = lrelu(dinv[d]*(sum + hb2[d]) + b)
__global__ void gather_norm(const int* __restrict__ rp, const int2* __restrict__ e_sw,
                            const unsigned short* __restrict__ hb,
                            const float* __restrict__ dinv, const float* __restrict__ b,
                            unsigned short* __restrict__ cat, int col_off, int n) {
    int node = (blockIdx.x * 256 + threadIdx.x) >> 6;
    if (node >= n) return;
    int lane = threadIdx.x & 63;
    int eg = lane >> 3;
    int f0 = (lane & 7) * 8;
    // hoisted: independent of the rp -> edge -> hb chain, overlaps its latency
    float di = dinv[node];
    us8 h = *(const us8*)&hb[(size_t)node * 64 + f0];
    int lo = rp[node], hi = rp[node + 1];
    float a[8] = {};
    for (int k = lo + eg; k < hi; k += 16) {
        int k1 = k + 8;
        int2 p0 = e_sw[k];
        int2 p1 = e_sw[k1 < hi ? k1 : k];
        float w0 = __int_as_float(p0.y);
        float w1 = k1 < hi ? __int_as_float(p1.y) : 0.f;
        us8 u0 = *(const us8*)&hb[(size_t)p0.x * 64 + f0];
        us8 u1 = *(const us8*)&hb[(size_t)p1.x * 64 + f0];
        a[0] += w0 * bf2f(u0.a.x) + w1 * bf2f(u1.a.x);
        a[1] += w0 * bf2f(u0.a.y) + w1 * bf2f(u1.a.y);
        a[2] += w0 * bf2f(u0.a.z) + w1 * bf2f(u1.a.z);
        a[3] += w0 * bf2f(u0.a.w) + w1 * bf2f(u1.a.w);
        a[4] += w0 * bf2f(u0.b.x) + w1 * bf2f(u1.b.x);
        a[5] += w0 * bf2f(u0.b.y) + w1 * bf2f(u1.b.y);
        a[6] += w0 * bf2f(u0.b.z) + w1 * bf2f(u1.b.z);
        a[7] += w0 * bf2f(u0.b.w) + w1 * bf2f(u1.b.w);
    }
#pragma unroll
    for (int j = 0; j < 8; ++j) {
        a[j] += __shfl_xor(a[j], 8, 64);
        a[j] += __shfl_xor(a[j], 16, 64);
        a[j] += __shfl_xor(a[j], 32, 64);
    }
    if (eg == 0) {
        float hs[8] = {bf2f(h.a.x), bf2f(h.a.y), bf2f(h.a.z), bf2f(h.a.w),
                       bf2f(h.b.x), bf2f(h.b.y), bf2f(h.b.z), bf2f(h.b.w)};
        unsigned short o[8];
#pragma unroll
        for (int j = 0; j < 8; ++j) o[j] = f2bf(lrelu(di * (a[j] + hs[j]) + b[f0 + j]));
        *(int4*)&cat[(size_t)node * 256 + col_off + f0] = *(int4*)o;
    }
}

// ---------------- MFMA hid GEMM (layers 2-4): cat-col[N x 64](bf16) @ W[64 x 64] -> dinv*out bf16 ----------------
__global__ __launch_bounds__(256) void gemm_hid_mfma(
    const unsigned short* __restrict__ in, int in_stride,
    const unsigned short* __restrict__ wT, const float* __restrict__ dinv,
    unsigned short* __restrict__ outb, int n_rows) {
    __shared__ __align__(16) char As[64 * 128];
    __shared__ __align__(16) char Bs[64 * 128];
    const int tid = threadIdx.x;
    const int wid = tid >> 6, lane = tid & 63;
    const int row0 = blockIdx.x * 64;
    const int lrow = lane & 15, kg = lane >> 4;
    {
        int row = tid >> 2, seg = tid & 3;
        int rr = row0 + row; if (rr >= n_rows) rr = n_rows - 1;
        const int4* g = (const int4*)&in[(size_t)rr * in_stride + seg * 16];
        int4 u0 = g[0], u1 = g[1];
        const int4* gb = (const int4*)&wT[(size_t)row * 64 + seg * 16];
        int4 v0 = gb[0], v1 = gb[1];
        int sw = (row & 7) << 4;
        int base = row * 128 + seg * 32;
        *(int4*)(As + (base ^ sw)) = u0;
        *(int4*)(As + ((base + 16) ^ sw)) = u1;
        *(int4*)(Bs + (base ^ sw)) = v0;
        *(int4*)(Bs + ((base + 16) ^ sw)) = v1;
    }
    __syncthreads();
    int arow = wid * 16 + lrow;
    int asw = (arow & 7) << 4;
    f32x4 acc[4] = {};
#pragma unroll
    for (int ks = 0; ks < 2; ++ks) {
        bf16x8 af = *(bf16x8*)(As + ((arow * 128 + ks * 64 + kg * 16) ^ asw));
#pragma unroll
        for (int cf = 0; cf < 4; ++cf) {
            int c = cf * 16 + lrow;
            bf16x8 bf = *(bf16x8*)(Bs + ((c * 128 + ks * 64 + kg * 16) ^ ((c & 7) << 4)));
            acc[cf] = __builtin_amdgcn_mfma_f32_16x16x32_bf16(af, bf, acc[cf], 0, 0, 0);
        }
    }
    int r4 = (lane >> 4) * 4;
#pragma unroll
    for (int reg = 0; reg < 4; ++reg) {
        int r = row0 + wid * 16 + r4 + reg;
        if (r >= n_rows) continue;
        float di = dinv[r];
#pragma unroll
        for (int cf = 0; cf < 4; ++cf)
            outb[(size_t)r * 64 + cf * 16 + lrow] = f2bf(acc[cf][reg] * di);
    }
}

// ---------------- MFMA layer-1 GEMM: x[N x 128](fp32) @ W1[128 x 64] -> bf16 hb ----------------
__global__ __launch_bounds__(256) void gemm_hid_mfma_x(
    const float* __restrict__ x, const unsigned short* __restrict__ w1T,
    unsigned short* __restrict__ outb, int n_rows) {
    __shared__ __align__(16) char As[64 * 256];
    __shared__ __align__(16) char Bs[64 * 256];
    const int tid = threadIdx.x;
    const int wid = tid >> 6, lane = tid & 63;
    const int row0 = blockIdx.x * 64;
    const int lrow = lane & 15, kg = lane >> 4;
    {
        int row = tid >> 2, seg = tid & 3;
        int rr = row0 + row; if (rr >= n_rows) rr = n_rows - 1;
        const float4* g = (const float4*)&x[(size_t)rr * 128 + seg * 32];
        const int4* gb = (const int4*)&w1T[(size_t)row * 128 + seg * 32];
        int sw = (row & 7) << 4;
        int base = row * 256 + seg * 64;
#pragma unroll
        for (int i = 0; i < 4; ++i) {
            float4 f0 = g[2 * i], f1 = g[2 * i + 1];
            unsigned short u[8] = {f2bf(f0.x), f2bf(f0.y), f2bf(f0.z), f2bf(f0.w),
                                   f2bf(f1.x), f2bf(f1.y), f2bf(f1.z), f2bf(f1.w)};
            *(int4*)(As + ((base + i * 16) ^ sw)) = *(int4*)u;
            *(int4*)(Bs + ((base + i * 16) ^ sw)) = gb[i];
        }
    }
    __syncthreads();
    int arow = wid * 16 + lrow;
    int asw = (arow & 7) << 4;
    f32x4 acc[4] = {};
#pragma unroll
    for (int ks = 0; ks < 4; ++ks) {
        bf16x8 af = *(bf16x8*)(As + ((arow * 256 + ks * 64 + kg * 16) ^ asw));
#pragma unroll
        for (int cf = 0; cf < 4; ++cf) {
            int c = cf * 16 + lrow;
            bf16x8 bf = *(bf16x8*)(Bs + ((c * 256 + ks * 64 + kg * 16) ^ ((c & 7) << 4)));
            acc[cf] = __builtin_amdgcn_mfma_f32_16x16x32_bf16(af, bf, acc[cf], 0, 0, 0);
        }
    }
    int r4 = (lane >> 4) * 4;
#pragma unroll
    for (int reg = 0; reg < 4; ++reg) {
        int r = row0 + wid * 16 + r4 + reg;
        if (r >= n_rows) continue;
#pragma unroll
        for (int cf = 0; cf < 4; ++cf)
            outb[(size_t)r * 64 + cf * 16 + lrow] = f2bf(acc[cf][reg]);
    }
}

// ---------------- final GEMM via MFMA: cat(bf16)[N x 256] @ Wh[256 x 128] + bh ----------------
__global__ __launch_bounds__(256) void gemm_out_mfma(
    const unsigned short* __restrict__ cat, const unsigned short* __restrict__ whT,
    const float* __restrict__ bh, float* __restrict__ out, int n_rows) {
    __shared__ __align__(16) char As[64 * 128];
    __shared__ __align__(16) char Bs[128 * 128];
    const int tid = threadIdx.x;
    const int wid = tid >> 6, lane = tid & 63;
    const int row0 = blockIdx.x * 64;
    const int lrow = lane & 15, kg = lane >> 4;
    f32x4 acc[8] = {};
    for (int kc = 0; kc < 4; ++kc) {
        __syncthreads();
        {
            int row = tid >> 2, seg = tid & 3;
            int rr = row0 + row; if (rr >= n_rows) rr = n_rows - 1;
            const int4* g = (const int4*)&cat[(size_t)rr * 256 + kc * 64 + seg * 16];
            int4 u0 = g[0], u1 = g[1];
            int sw = (row & 7) << 4;
            int base = row * 128 + seg * 32;
            *(int4*)(As + (base ^ sw)) = u0;
            *(int4*)(As + ((base + 16) ^ sw)) = u1;
        }
        {
            int c = tid >> 1, seg = tid & 1;
            const int4* g = (const int4*)&whT[(size_t)c * 256 + kc * 64 + seg * 32];
            int sw = (c & 7) << 4;
            int base = c * 128 + seg * 64;
#pragma unroll
            for (int i = 0; i < 4; ++i)
                *(int4*)(Bs + ((base + i * 16) ^ sw)) = g[i];
        }
        __syncthreads();
        int arow = wid * 16 + lrow;
        int asw = (arow & 7) << 4;
#pragma unroll
        for (int ks = 0; ks < 2; ++ks) {
            bf16x8 af = *(bf16x8*)(As + ((arow * 128 + ks * 64 + kg * 16) ^ asw));
#pragma unroll
            for (int cf = 0; cf < 8; ++cf) {
                int c = cf * 16 + lrow;
                bf16x8 bf = *(bf16x8*)(Bs + ((c * 128 + ks * 64 + kg * 16) ^ ((c & 7) << 4)));
                acc[cf] = __builtin_amdgcn_mfma_f32_16x16x32_bf16(af, bf, acc[cf], 0, 0, 0);
            }
        }
    }
    int lrow4 = (lane >> 4) * 4;
#pragma unroll
    for (int cf = 0; cf < 8; ++cf) {
        int col = cf * 16 + lrow;
        float bias = bh[col];
#pragma unroll
        for (int reg = 0; reg < 4; ++reg) {
            int r = row0 + wid * 16 + lrow4 + reg;
            if (r < n_rows) out[(size_t)r * 128 + col] = acc[cf][reg] + bias;
        }
    }
}

extern "C" void kernel_launch(void* const* d_in, const int* in_sizes, int n_in,
                              void* d_out, int out_size, void* d_ws, size_t ws_size,
                              hipStream_t stream) {
    const float* x  = (const float*)d_in[0];
    const int*   ei = (const int*)d_in[1];
    const float* ew = (const float*)d_in[2];
    const float* W1 = (const float*)d_in[3];
    const float* b1 = (const float*)d_in[4];
    const float* W2 = (const float*)d_in[5];
    const float* b2 = (const float*)d_in[6];
    const float* W3 = (const float*)d_in[7];
    const float* b3 = (const float*)d_in[8];
    const float* W4 = (const float*)d_in[9];
    const float* b4 = (const float*)d_in[10];
    const float* Wh = (const float*)d_in[11];
    const float* bh = (const float*)d_in[12];

    const int E = in_sizes[2];          // 800000
    const int N = in_sizes[0] / 128;    // 50000
    const int* src = ei;
    const int* dst = ei + E;

    char* p = (char*)d_ws;
    unsigned short* cat     = (unsigned short*)p; p += (size_t)N * 256 * 2;
    unsigned short* hb      = (unsigned short*)p; p += (size_t)N * 64 * 2;
    unsigned short* wht     = (unsigned short*)p; p += (size_t)128 * 256 * 2;
    unsigned short* w1t     = (unsigned short*)p; p += (size_t)64 * 128 * 2;
    unsigned short* w2t     = (unsigned short*)p; p += (size_t)64 * 64 * 2;
    unsigned short* w3t     = (unsigned short*)p; p += (size_t)64 * 64 * 2;
    unsigned short* w4t     = (unsigned short*)p; p += (size_t)64 * 64 * 2;
    ull*            packed4 = (ull*)p;            p += (size_t)N * 4 * 8;
    float*          dinv    = (float*)p;          p += (size_t)N * 4;
    int*            row_ptr = (int*)p;            p += (size_t)(N + 4) * 4;
    int*            bsum    = (int*)p;            p += (size_t)64 * 4;
    int4*           bases   = (int4*)p;           p += (size_t)N * 16;
    int*            rank    = (int*)p;            p += (size_t)E * 4;
    int2*           e_sw    = (int2*)p;           p += (size_t)E * 8;
    float* out = (float*)d_out;

    int eb   = (E + 255) / 256;
    int nb64 = (N * 64 + 255) / 256;
    int gb64 = (N + 63) / 64;
    int sb   = (N + 1023) / 1024;       // <= 64
    int s3b  = ((N + 3) / 4 + 256) / 256;
    int nz   = N * 2;
    int pb   = (nz > 256 * 128 ? nz : 256 * 128) / 256 + 1;

    // ---- prep + CSR build ----
    prep_kernel<<<pb, 256, 0, stream>>>(Wh, wht, W1, w1t, W2, w2t, W3, w3t, W4, w4t,
                                        (float4*)packed4, nz);
    histo_kernel<<<eb, 256, 0, stream>>>(dst, ew, packed4, rank, E, N);
    scan1_kernel<<<sb, 256, 0, stream>>>(packed4, row_ptr, bases, bsum, dinv, N);
    scan3_kernel<<<s3b, 256, 0, stream>>>(row_ptr, bases, bsum, sb, N, E);
    fill_kernel<<<eb, 256, 0, stream>>>(src, dst, ew, rank, bases, e_sw, E);

    // ---- layer 1 (no norm) ----
    gemm_hid_mfma_x<<<gb64, 256, 0, stream>>>(x, w1t, hb, N);
    gather_plain<<<nb64, 256, 0, stream>>>(row_ptr, e_sw, hb, b1, cat, N);

    // ---- layers 2-4 (normalized; hb holds dinv-scaled hidden) ----
    const unsigned short* Wt[3] = {w2t, w3t, w4t};
    const float* bl[3] = {b2, b3, b4};
    for (int l = 1; l < 4; ++l) {
        gemm_hid_mfma<<<gb64, 256, 0, stream>>>(cat + (size_t)(l - 1) * 64, 256,
                                                Wt[l - 1], dinv, hb, N);
        gather_norm<<<nb64, 256, 0, stream>>>(row_ptr, e_sw, hb, dinv,
                                              bl[l - 1], cat, l * 64, N);
    }

    // ---- final projection (MFMA) ----
    gemm_out_mfma<<<gb64, 256, 0, stream>>>(cat, wht, bh, out, N);
}